// Round 5
// baseline (226.489 us; speedup 1.0000x reference)
//
#include <hip/hip_runtime.h>
#include <math.h>

// ---------------------------------------------------------------------------
// EstimatorQNNHybrid, round 5:
//  - k_cnn: __launch_bounds__(256,4) -> VGPR cap 128, kills R4's scratch
//    spill (VGPR=36, 36MB scratch writes).
//  - k_tail: merged quantum+final. 32 co-resident blocks; BN2 grid sync via
//    device-scope atomic counter + spin (graph-capture safe). q_pre buffer
//    eliminated: bn1 output (a[]) and q[] stay in registers across the sync.
// Nodes: k_prep -> k_cnn -> k_tail.
// ws: bins1[256] bins2[256] M[512] w2t[1152] counter @2176. (~8.7 KB)
// ---------------------------------------------------------------------------

#define XS_S 34      // padded 30x34 input tile
#define H1_S 18      // padded 16x18 per-channel conv1 output

__device__ __forceinline__ float2 cmul(float2 a, float2 b) {
    return make_float2(a.x * b.x - a.y * b.y, a.x * b.y + a.y * b.x);
}
__device__ __forceinline__ float2 cadd(float2 a, float2 b) {
    return make_float2(a.x + b.x, a.y + b.y);
}

// ================= gate helpers (fixed-tail folding) ========================
__device__ __forceinline__ void apply_1q(const float2* src, float2* dst, int t,
                                         float2 g00, float2 g01, float2 g10, float2 g11, int p)
{
    int j = t >> 4, i = t & 15;
    int jb = (j >> p) & 1;
    int k0 = j & ~(1 << p);
    int k1 = j | (1 << p);
    float2 a0 = src[k0 * 16 + i], a1 = src[k1 * 16 + i];
    float2 r = jb ? cadd(cmul(g10, a0), cmul(g11, a1))
                  : cadd(cmul(g00, a0), cmul(g01, a1));
    dst[j * 16 + i] = r;
}

__device__ __forceinline__ void apply_ctrl(const float2* src, float2* dst, int t,
                                           float2 g00, float2 g01, float2 g10, float2 g11,
                                           int pc, int pt)
{
    int j = t >> 4, i = t & 15;
    float2 r;
    if (((j >> pc) & 1) == 0) {
        r = src[j * 16 + i];
    } else {
        int jb = (j >> pt) & 1;
        int k0 = j & ~(1 << pt);
        int k1 = j | (1 << pt);
        float2 a0 = src[k0 * 16 + i], a1 = src[k1 * 16 + i];
        r = jb ? cadd(cmul(g10, a0), cmul(g11, a1))
               : cadd(cmul(g00, a0), cmul(g01, a1));
    }
    dst[j * 16 + i] = r;
}

// ========== K0: zero bins/counter + transpose w2 + build fused M ===========
__global__ __launch_bounds__(256) void k_prep(
    const float* __restrict__ w2, const float* __restrict__ theta,
    const float* __restrict__ u_re, const float* __restrict__ u_im,
    float* __restrict__ ws)
{
    __shared__ float2 A[256], B[256];
    const int t = threadIdx.x;
    ws[t] = 0.f;            // bins1
    ws[256 + t] = 0.f;      // bins2
    if (t == 0) ((unsigned int*)ws)[2176] = 0u;   // sync counter
    for (int i = t; i < 1152; i += 256) {
        int oc = i / 72, rem = i % 72;        // rem = ic*9+k
        ws[1024 + rem * 16 + oc] = w2[i];
    }
    A[t] = make_float2(u_re[t], u_im[t]);
    float th0 = theta[0], th1 = theta[1], th2 = theta[2], th3 = theta[3];
    __syncthreads();
    float c0 = cosf(0.5f * th0), s0 = sinf(0.5f * th0);
    apply_1q(A, B, t, make_float2(c0, 0), make_float2(0, -s0),
                      make_float2(0, -s0), make_float2(c0, 0), 3);   // RX wire0
    __syncthreads();
    float c1 = cosf(0.5f * th1), s1 = sinf(0.5f * th1);
    apply_1q(B, A, t, make_float2(c1, 0), make_float2(-s1, 0),
                      make_float2(s1, 0), make_float2(c1, 0), 2);    // RY wire1
    __syncthreads();
    float c2 = cosf(0.5f * th2), s2 = sinf(0.5f * th2);
    apply_1q(A, B, t, make_float2(c2, -s2), make_float2(0, 0),
                      make_float2(0, 0), make_float2(c2, s2), 1);    // RZ wire2
    __syncthreads();
    float c3 = cosf(0.5f * th3), s3 = sinf(0.5f * th3);
    apply_ctrl(B, A, t, make_float2(c3, 0), make_float2(0, -s3),
                        make_float2(0, -s3), make_float2(c3, 0), 3, 0); // CRX w0->w3
    __syncthreads();
    const float hh = 0.70710678118654752440f;
    apply_1q(A, B, t, make_float2(hh, 0), make_float2(hh, 0),
                      make_float2(hh, 0), make_float2(-hh, 0), 0);   // H wire3
    __syncthreads();
    apply_1q(B, A, t, make_float2(0.5f, 0.5f), make_float2(0.5f, -0.5f),
                      make_float2(0.5f, -0.5f), make_float2(0.5f, 0.5f), 1); // SX wire2
    __syncthreads();
    apply_ctrl(A, B, t, make_float2(0, 0), make_float2(1, 0),
                        make_float2(1, 0), make_float2(0, 0), 0, 3); // CX w3->w0
    __syncthreads();
    ws[512 + 2 * t]     = B[t].x;
    ws[512 + 2 * t + 1] = B[t].y;
}

// ========================= K1: fused CNN per sample =========================
// __launch_bounds__(256,4): VGPR cap 128 (needs ~75) -> no scratch spill,
// 4 blocks/CU. (Plain (256) let the allocator cap at 36 VGPR and spill 36MB.)
__global__ __launch_bounds__(256, 4) void k_cnn(
    const float* __restrict__ x,
    const float* __restrict__ w1, const float* __restrict__ b1,
    const float* __restrict__ w2t, const float* __restrict__ b2,
    const float* __restrict__ fw1, const float* __restrict__ fb1,
    const float* __restrict__ fw2, const float* __restrict__ fb2,
    float* __restrict__ out_pre, float* __restrict__ bins1)
{
    __shared__ __align__(16) float xs[30 * XS_S];        // 1020
    __shared__ __align__(16) float h1s[8 * 16 * H1_S];   // 2304
    __shared__ __align__(16) float h2p[144 * 16];        // pre-pool conv2 [pos][16oc]
    __shared__ float pool_s[16];

    const int t = threadIdx.x;
    const int b = blockIdx.x;
    const float* xg = x + b * 784;

    // ---- phase A: pad borders + fill interior ----
    if (t < 59) {
        if (t < 30) xs[t] = 0.f;
        else        xs[(t - 29) * XS_S] = 0.f;
    }
    if (t < 216) {
        int pl = t / 27, r = t % 27;
        if (r < 14) h1s[pl * 288 + r] = 0.f;
        else        h1s[pl * 288 + (r - 13) * H1_S] = 0.f;
    }
    if (t < 196) {
        float4 v = ((const float4*)xg)[t];
        int p = t * 4;
        int yy = p / 28, xx = p % 28;
        int base = (yy + 1) * XS_S + xx + 1;
        xs[base]     = v.x;
        xs[base + 1] = v.y;
        xs[base + 2] = v.z;
        xs[base + 3] = v.w;
    }
    __syncthreads();

    // ---- conv1 (1->8) + relu + 2x2 maxpool: 169 threads = 13x13 ----
    if (t < 169) {
        const int py = t / 13, px = t % 13;
        float patch[4][4];
        #pragma unroll
        for (int dr = 0; dr < 4; ++dr) {
            int base = (2 * py + dr) * XS_S + 2 * px;
            float2 a = *(const float2*)&xs[base];
            float2 c = *(const float2*)&xs[base + 2];
            patch[dr][0] = a.x; patch[dr][1] = a.y;
            patch[dr][2] = c.x; patch[dr][3] = c.y;
        }
        float acc[8][2][2];
        #pragma unroll
        for (int c = 0; c < 8; ++c)
            #pragma unroll
            for (int dy = 0; dy < 2; ++dy)
                #pragma unroll
                for (int dx = 0; dx < 2; ++dx) acc[c][dy][dx] = 0.f;
        #pragma unroll
        for (int k = 0; k < 9; ++k) {
            const int ky = k / 3, kx = k % 3;
            #pragma unroll
            for (int c = 0; c < 8; ++c) {
                float w = w1[c * 9 + k];                    // uniform -> s_load
                #pragma unroll
                for (int dy = 0; dy < 2; ++dy)
                    #pragma unroll
                    for (int dx = 0; dx < 2; ++dx)
                        acc[c][dy][dx] = fmaf(patch[dy + ky][dx + kx], w, acc[c][dy][dx]);
            }
        }
        #pragma unroll
        for (int c = 0; c < 8; ++c) {
            float m = fmaxf(fmaxf(acc[c][0][0], acc[c][0][1]),
                            fmaxf(acc[c][1][0], acc[c][1][1])) + b1[c];
            h1s[c * 288 + (py + 1) * H1_S + (px + 1)] = fmaxf(m, 0.f);
        }
    }
    __syncthreads();

    // ---- conv2 (8->16): 144 threads = pre-pool pos in 12x12, acc[16] ----
    if (t < 144) {
        const int y = t / 12, x = t % 12;
        const int x0 = x & ~1;
        const bool odd = (x & 1) != 0;
        float acc[16];
        #pragma unroll
        for (int oc = 0; oc < 16; ++oc) acc[oc] = 0.f;
        #pragma unroll
        for (int ic = 0; ic < 8; ++ic) {
            float p[3][4];
            #pragma unroll
            for (int dr = 0; dr < 3; ++dr) {
                int base = ic * 288 + (y + dr) * H1_S + x0;
                float2 a = *(const float2*)&h1s[base];
                float2 c = *(const float2*)&h1s[base + 2];
                p[dr][0] = a.x; p[dr][1] = a.y; p[dr][2] = c.x; p[dr][3] = c.y;
            }
            float pv[9];
            #pragma unroll
            for (int dr = 0; dr < 3; ++dr)
                #pragma unroll
                for (int j = 0; j < 3; ++j)
                    pv[dr * 3 + j] = odd ? p[dr][j + 1] : p[dr][j];
            #pragma unroll
            for (int k = 0; k < 9; ++k) {
                const float* wrow = w2t + (ic * 9 + k) * 16;  // uniform -> s_load
                #pragma unroll
                for (int oc = 0; oc < 16; ++oc)
                    acc[oc] = fmaf(pv[k], wrow[oc], acc[oc]);
            }
        }
        const int hbase = t * 16;
        #pragma unroll
        for (int j = 0; j < 4; ++j)
            *(float4*)&h2p[hbase + 4 * j] =
                make_float4(acc[4 * j], acc[4 * j + 1], acc[4 * j + 2], acc[4 * j + 3]);
    }
    __syncthreads();

    // ---- maxpool(2x2) + bias + relu + avg 6x6: 64 lanes ----
    if (t < 64) {
        const int oc = t >> 2, q = t & 3;
        const float bias = b2[oc];
        float s = 0.f;
        #pragma unroll
        for (int r = 0; r < 9; ++r) {
            int idx = q * 9 + r;
            int pr = idx / 6, pc = idx % 6;
            int p00 = (2 * pr * 12 + 2 * pc) * 16 + oc;
            float m = fmaxf(fmaxf(h2p[p00], h2p[p00 + 16]),
                            fmaxf(h2p[p00 + 192], h2p[p00 + 208]));
            s += fmaxf(m + bias, 0.f);
        }
        s += __shfl_xor(s, 1);
        s += __shfl_xor(s, 2);
        if (q == 0) pool_s[oc] = s * (1.f / 36.f);
    }
    __syncthreads();

    // ---- fc1 (16->64) + relu + fc2 (64->4) in wave 0 ----
    if (t < 64) {
        const float4* f4 = (const float4*)(fw1 + t * 16);
        float4 wa = f4[0], wb = f4[1], wc = f4[2], wd = f4[3];
        float a1 = fb1[t];
        a1 = fmaf(pool_s[0],  wa.x, a1); a1 = fmaf(pool_s[1],  wa.y, a1);
        a1 = fmaf(pool_s[2],  wa.z, a1); a1 = fmaf(pool_s[3],  wa.w, a1);
        a1 = fmaf(pool_s[4],  wb.x, a1); a1 = fmaf(pool_s[5],  wb.y, a1);
        a1 = fmaf(pool_s[6],  wb.z, a1); a1 = fmaf(pool_s[7],  wb.w, a1);
        a1 = fmaf(pool_s[8],  wc.x, a1); a1 = fmaf(pool_s[9],  wc.y, a1);
        a1 = fmaf(pool_s[10], wc.z, a1); a1 = fmaf(pool_s[11], wc.w, a1);
        a1 = fmaf(pool_s[12], wd.x, a1); a1 = fmaf(pool_s[13], wd.y, a1);
        a1 = fmaf(pool_s[14], wd.z, a1); a1 = fmaf(pool_s[15], wd.w, a1);
        float f = fmaxf(a1, 0.f);
        float p0 = f * fw2[t];
        float p1 = f * fw2[64 + t];
        float p2 = f * fw2[128 + t];
        float p3 = f * fw2[192 + t];
        #pragma unroll
        for (int off = 32; off > 0; off >>= 1) {
            p0 += __shfl_down(p0, off);
            p1 += __shfl_down(p1, off);
            p2 += __shfl_down(p2, off);
            p3 += __shfl_down(p3, off);
        }
        if (t == 0) {
            float v0 = p0 + fb2[0], v1 = p1 + fb2[1], v2 = p2 + fb2[2], v3 = p3 + fb2[3];
            ((float4*)out_pre)[b] = make_float4(v0, v1, v2, v3);
            float* bin = bins1 + ((b & 31) << 3);
            atomicAdd(&bin[0], v0);            atomicAdd(&bin[1], v1);
            atomicAdd(&bin[2], v2);            atomicAdd(&bin[3], v3);
            atomicAdd(&bin[4], v0 * v0);       atomicAdd(&bin[5], v1 * v1);
            atomicAdd(&bin[6], v2 * v2);       atomicAdd(&bin[7], v3 * v3);
        }
    }
}

// ====== K2: BN1 reduce + quantum + BN2 (spin grid-sync) + final ============
// 32 blocks, always co-resident on 256 CUs -> atomic-counter spin is safe.
__global__ __launch_bounds__(256) void k_tail(
    float* __restrict__ out_pre,          // == d_out, read + final write
    const float* __restrict__ bins1,
    const float* __restrict__ ng, const float* __restrict__ nb,
    const float* __restrict__ Mg,
    float* __restrict__ bins2,
    const float* __restrict__ qg, const float* __restrict__ qb,
    unsigned int* __restrict__ counter)
{
    __shared__ float red[256];
    __shared__ float ss1[8], ss2[8];
    __shared__ float2 Ms[256];
    const int t = threadIdx.x;

    red[t] = bins1[t];
    Ms[t] = make_float2(Mg[2 * t], Mg[2 * t + 1]);
    __syncthreads();
    if (t < 8) {
        float s = 0.f;
        for (int bb = 0; bb < 32; ++bb) s += red[bb * 8 + t];
        red[t] = s;
    }
    if (t < 4) {
        float mean = red[t] * (1.f / 8192.f);
        float var = red[4 + t] * (1.f / 8192.f) - mean * mean;
        float sc = ng[t] * rsqrtf(var + 1e-5f);
        ss1[t] = sc;
        ss1[4 + t] = nb[t] - mean * sc;
    }
    __syncthreads();

    // ---- per-sample: BN1 -> encoder product state -> M*psi -> <Z_w> ----
    const int sidx = blockIdx.x * 256 + t;
    float4 o4 = ((const float4*)out_pre)[sidx];
    float a[4];                                  // bn1 output = encoder angles
    a[0] = fmaf(ss1[0], o4.x, ss1[4]);
    a[1] = fmaf(ss1[1], o4.y, ss1[5]);
    a[2] = fmaf(ss1[2], o4.z, ss1[6]);
    a[3] = fmaf(ss1[3], o4.w, ss1[7]);
    float2 v[4][2];
    #pragma unroll
    for (int w = 0; w < 4; ++w) {
        float s, c;
        __sincosf(0.5f * a[w], &s, &c);
        float2 v0 = make_float2(c * c, -c * s);
        float2 v1 = make_float2(s * c, s * s);
        float2 n0 = make_float2(c * v0.x + s * v1.y, c * v0.y - s * v1.x);
        float2 n1 = make_float2(s * v0.y + c * v1.x, -s * v0.x + c * v1.y);
        v[w][0] = make_float2(c * n0.x - s * n1.x, c * n0.y - s * n1.y);
        v[w][1] = make_float2(s * n0.x + c * n1.x, s * n0.y + c * n1.y);
    }
    float2 st[16];
    #pragma unroll
    for (int idx = 0; idx < 16; ++idx) {
        float2 p = cmul(v[0][(idx >> 3) & 1], v[1][(idx >> 2) & 1]);
        p = cmul(p, v[2][(idx >> 1) & 1]);
        st[idx] = cmul(p, v[3][idx & 1]);
    }
    float q[4] = {0.f, 0.f, 0.f, 0.f};
    #pragma unroll
    for (int j = 0; j < 16; ++j) {
        float2 acc = make_float2(0.f, 0.f);
        #pragma unroll
        for (int i = 0; i < 16; ++i) {
            float2 mm = Ms[j * 16 + i];
            acc.x = fmaf(mm.x, st[i].x, acc.x);
            acc.x = fmaf(-mm.y, st[i].y, acc.x);
            acc.y = fmaf(mm.x, st[i].y, acc.y);
            acc.y = fmaf(mm.y, st[i].x, acc.y);
        }
        float pr = acc.x * acc.x + acc.y * acc.y;
        q[0] += ((j >> 3) & 1) ? -pr : pr;
        q[1] += ((j >> 2) & 1) ? -pr : pr;
        q[2] += ((j >> 1) & 1) ? -pr : pr;
        q[3] += (j & 1) ? -pr : pr;
    }

    // ---- BN2 partials: per-block reduce -> device-scope publish ----
    float vals[8] = {q[0], q[1], q[2], q[3],
                     q[0] * q[0], q[1] * q[1], q[2] * q[2], q[3] * q[3]};
    #pragma unroll
    for (int off = 32; off > 0; off >>= 1)
        #pragma unroll
        for (int k = 0; k < 8; ++k) vals[k] += __shfl_down(vals[k], off);
    if ((t & 63) == 0) {
        int wid = t >> 6;
        #pragma unroll
        for (int k = 0; k < 8; ++k) red[wid * 8 + k] = vals[k];
    }
    __syncthreads();
    if (t < 8) {
        float s = red[t] + red[8 + t] + red[16 + t] + red[24 + t];
        __hip_atomic_store(&bins2[blockIdx.x * 8 + t], s,
                           __ATOMIC_RELEASE, __HIP_MEMORY_SCOPE_AGENT);
    }
    __syncthreads();

    // ---- grid sync: 32 co-resident blocks spin on device-scope counter ----
    if (t == 0) {
        __threadfence();
        atomicAdd(counter, 1u);
        while (__hip_atomic_load(counter, __ATOMIC_ACQUIRE,
                                 __HIP_MEMORY_SCOPE_AGENT) < 32u) {
            __builtin_amdgcn_s_sleep(4);
        }
    }
    __syncthreads();

    // ---- BN2 stats from all 32 blocks' bins ----
    red[t] = __hip_atomic_load(&bins2[t], __ATOMIC_RELAXED, __HIP_MEMORY_SCOPE_AGENT);
    __syncthreads();
    if (t < 8) {
        float s = 0.f;
        for (int bb = 0; bb < 32; ++bb) s += red[bb * 8 + t];
        red[t] = s;
    }
    if (t < 4) {
        float m2 = red[t] * (1.f / 8192.f);
        float v2 = red[4 + t] * (1.f / 8192.f) - m2 * m2;
        float sc = qg[t] * rsqrtf(v2 + 1e-5f);
        ss2[t] = sc;
        ss2[4 + t] = qb[t] - m2 * sc;
    }
    __syncthreads();

    // ---- final: out = bn1(out_pre) + bn2(q); both still in registers ----
    float4 r;
    r.x = a[0] + fmaf(ss2[0], q[0], ss2[4]);
    r.y = a[1] + fmaf(ss2[1], q[1], ss2[5]);
    r.z = a[2] + fmaf(ss2[2], q[2], ss2[6]);
    r.w = a[3] + fmaf(ss2[3], q[3], ss2[7]);
    ((float4*)out_pre)[sidx] = r;
}

// ===========================================================================
extern "C" void kernel_launch(void* const* d_in, const int* in_sizes, int n_in,
                              void* d_out, int out_size, void* d_ws, size_t ws_size,
                              hipStream_t stream)
{
    const float* x     = (const float*)d_in[0];
    const float* w1    = (const float*)d_in[1];
    const float* b1    = (const float*)d_in[2];
    const float* w2    = (const float*)d_in[3];
    const float* b2    = (const float*)d_in[4];
    const float* fw1   = (const float*)d_in[5];
    const float* fb1   = (const float*)d_in[6];
    const float* fw2   = (const float*)d_in[7];
    const float* fb2   = (const float*)d_in[8];
    const float* ng    = (const float*)d_in[9];
    const float* nb    = (const float*)d_in[10];
    const float* theta = (const float*)d_in[11];
    const float* ure   = (const float*)d_in[12];
    const float* uim   = (const float*)d_in[13];
    const float* qg    = (const float*)d_in[14];
    const float* qb    = (const float*)d_in[15];

    float* ws    = (float*)d_ws;
    float* bins1 = ws;                        // 256
    float* bins2 = ws + 256;                  // 256
    float* Mg    = ws + 512;                  // 512
    float* w2t   = ws + 1024;                 // 1152
    unsigned int* counter = (unsigned int*)(ws + 2176);
    float* out_pre = (float*)d_out;

    k_prep<<<1, 256, 0, stream>>>(w2, theta, ure, uim, ws);
    k_cnn<<<8192, 256, 0, stream>>>(x, w1, b1, w2t, b2, fw1, fb1, fw2, fb2,
                                    out_pre, bins1);
    k_tail<<<32, 256, 0, stream>>>(out_pre, bins1, ng, nb, Mg, bins2, qg, qb,
                                   counter);
}

// Round 6
// 164.525 us; speedup vs baseline: 1.3766x; 1.3766x over previous
//
#include <hip/hip_runtime.h>
#include <math.h>

// ---------------------------------------------------------------------------
// EstimatorQNNHybrid, round 6: 2-kernel pipeline, LDS-broadcast weights.
//  k_cnn : per-sample CNN. conv1 169 lanes (13x13 pooled region); conv2
//          192 lanes = (oc 0..15, row 0..11), acc[12]/thread, weights from
//          LDS [ic*9+k][16oc] (16 banks x 4-way broadcast = conflict-free);
//          wave 3 stages the w2 transpose during conv1. Pool via shfl.
//          No atomics, no bins. Writes out_pre only. Zeroes sync counters.
//  k_tail: 32 co-resident blocks. BN1 stats from out_pre (slice partials +
//          spin grid-sync #1, M build overlaps the wait), quantum, BN2
//          (grid-sync #2), final combine. R5's verified sync pattern.
// ws: counters[2] @0, bins1[256] @16, bins2[256] @272 (floats).
// ---------------------------------------------------------------------------

#define XS_S 34      // 29x34 padded input (row0/col0 = zero pad)
#define H1_S 20      // 14x20 padded conv1-pooled planes (row0/col0 pad)
#define H1_P 280     // 14*20 plane stride

__device__ __forceinline__ float2 cmul(float2 a, float2 b) {
    return make_float2(a.x * b.x - a.y * b.y, a.x * b.y + a.y * b.x);
}
__device__ __forceinline__ float2 cadd(float2 a, float2 b) {
    return make_float2(a.x + b.x, a.y + b.y);
}

__device__ __forceinline__ void apply_1q(const float2* src, float2* dst, int t,
                                         float2 g00, float2 g01, float2 g10, float2 g11, int p)
{
    int j = t >> 4, i = t & 15;
    int jb = (j >> p) & 1;
    int k0 = j & ~(1 << p);
    int k1 = j | (1 << p);
    float2 a0 = src[k0 * 16 + i], a1 = src[k1 * 16 + i];
    float2 r = jb ? cadd(cmul(g10, a0), cmul(g11, a1))
                  : cadd(cmul(g00, a0), cmul(g01, a1));
    dst[j * 16 + i] = r;
}

__device__ __forceinline__ void apply_ctrl(const float2* src, float2* dst, int t,
                                           float2 g00, float2 g01, float2 g10, float2 g11,
                                           int pc, int pt)
{
    int j = t >> 4, i = t & 15;
    float2 r;
    if (((j >> pc) & 1) == 0) {
        r = src[j * 16 + i];
    } else {
        int jb = (j >> pt) & 1;
        int k0 = j & ~(1 << pt);
        int k1 = j | (1 << pt);
        float2 a0 = src[k0 * 16 + i], a1 = src[k1 * 16 + i];
        r = jb ? cadd(cmul(g10, a0), cmul(g11, a1))
               : cadd(cmul(g00, a0), cmul(g01, a1));
    }
    dst[j * 16 + i] = r;
}

// ========================= K1: fused CNN per sample =========================
__global__ __launch_bounds__(256, 6) void k_cnn(
    const float* __restrict__ x,
    const float* __restrict__ w1, const float* __restrict__ b1,
    const float* __restrict__ w2, const float* __restrict__ b2,
    const float* __restrict__ fw1, const float* __restrict__ fb1,
    const float* __restrict__ fw2, const float* __restrict__ fb2,
    float* __restrict__ out_pre, unsigned int* __restrict__ counters)
{
    __shared__ __align__(16) float xs[29 * XS_S];    // 986
    __shared__ __align__(16) float h1s[8 * H1_P];    // 2240
    __shared__ __align__(16) float w2s[72 * 16];     // [(ic*9+k)][16oc]
    __shared__ float w1t[72];                        // [k][8c]
    __shared__ float b1t[8], b2t[16];
    __shared__ float pool_part[48];                  // 3 waves x 16 oc
    __shared__ float pool_s[16];

    const int t = threadIdx.x;
    const int b = blockIdx.x;
    const float* xg = x + b * 784;

    // ---- phase A: pads + interior + small weights (disjoint writes) ----
    if (b == 0 && t < 2) counters[t] = 0u;           // sync counters for k_tail
    if (t < 57) {
        if (t < 29) xs[t] = 0.f;
        else        xs[(t - 28) * XS_S] = 0.f;       // col 0, rows 1..28
    }
    if (t < 216) {                                   // h1 pads: row0(14)+col0(13) per plane
        int pl = t / 27, r = t % 27;
        if (r < 14) h1s[pl * H1_P + r] = 0.f;
        else        h1s[pl * H1_P + (r - 13) * H1_S] = 0.f;
    }
    if (t >= 64 && t < 136) {                        // w1 [c][k] -> [k][8c]
        int i = t - 64;
        w1t[(i % 9) * 8 + (i / 9)] = w1[i];
    }
    if (t < 196) {                                   // interior, 196 float4
        float4 v = ((const float4*)xg)[t];
        int p = t * 4;
        int yy = p / 28, xx = p % 28;
        int base = (yy + 1) * XS_S + xx + 1;
        xs[base] = v.x; xs[base + 1] = v.y; xs[base + 2] = v.z; xs[base + 3] = v.w;
    }
    if (t < 8)  b1t[t] = b1[t];
    if (t < 16) b2t[t] = b2[t];
    __syncthreads();

    // ---- conv1 (1->8)+relu+pool: 169 lanes = pooled 13x13; wave3 stages w2t
    if (t < 169) {
        const int py = t / 13, px = t % 13;
        float patch[4][4];
        #pragma unroll
        for (int dr = 0; dr < 4; ++dr) {
            int base = (2 * py + dr) * XS_S + 2 * px;
            float2 a = *(const float2*)&xs[base];
            float2 c = *(const float2*)&xs[base + 2];
            patch[dr][0] = a.x; patch[dr][1] = a.y;
            patch[dr][2] = c.x; patch[dr][3] = c.y;
        }
        float acc[8][2][2];
        #pragma unroll
        for (int c = 0; c < 8; ++c)
            #pragma unroll
            for (int dy = 0; dy < 2; ++dy)
                #pragma unroll
                for (int dx = 0; dx < 2; ++dx) acc[c][dy][dx] = 0.f;
        #pragma unroll
        for (int k = 0; k < 9; ++k) {
            const int ky = k / 3, kx = k % 3;
            float4 wA = *(const float4*)&w1t[k * 8];     // same addr all lanes
            float4 wB = *(const float4*)&w1t[k * 8 + 4];
            float w8[8] = {wA.x, wA.y, wA.z, wA.w, wB.x, wB.y, wB.z, wB.w};
            #pragma unroll
            for (int c = 0; c < 8; ++c)
                #pragma unroll
                for (int dy = 0; dy < 2; ++dy)
                    #pragma unroll
                    for (int dx = 0; dx < 2; ++dx)
                        acc[c][dy][dx] = fmaf(patch[dy + ky][dx + kx], w8[c], acc[c][dy][dx]);
        }
        #pragma unroll
        for (int c = 0; c < 8; ++c) {
            float m = fmaxf(fmaxf(acc[c][0][0], acc[c][0][1]),
                            fmaxf(acc[c][1][0], acc[c][1][1])) + b1t[c];
            h1s[c * H1_P + (py + 1) * H1_S + (px + 1)] = fmaxf(m, 0.f);
        }
    } else if (t >= 192) {
        // wave 3: transpose w2 [oc][ic][k] -> w2s[(ic*9+k)][16oc]
        for (int i = t - 192; i < 1152; i += 64) {
            int oc = i / 72, rem = i % 72;
            w2s[rem * 16 + oc] = w2[i];
        }
    }
    __syncthreads();

    // ---- conv2 (8->16): 192 lanes = (oc, row); acc[12] per thread ----------
    float rowsum = 0.f;           // per-lane pooled-row sum (valid on even rows)
    {
        const int oc = t & 15, y = t >> 4;     // y in 0..11 for t<192
        float acc[12];
        #pragma unroll
        for (int j = 0; j < 12; ++j) acc[j] = 0.f;
        if (t < 192) {
            #pragma unroll 2
            for (int ic = 0; ic < 8; ++ic) {
                float r[3][14];
                #pragma unroll
                for (int dr = 0; dr < 3; ++dr) {
                    int base = ic * H1_P + (y + dr) * H1_S;   // 16B aligned
                    float4 a = *(const float4*)&h1s[base];
                    float4 bb = *(const float4*)&h1s[base + 4];
                    float4 c = *(const float4*)&h1s[base + 8];
                    float2 d = *(const float2*)&h1s[base + 12];
                    r[dr][0] = a.x;  r[dr][1] = a.y;  r[dr][2] = a.z;  r[dr][3] = a.w;
                    r[dr][4] = bb.x; r[dr][5] = bb.y; r[dr][6] = bb.z; r[dr][7] = bb.w;
                    r[dr][8] = c.x;  r[dr][9] = c.y;  r[dr][10] = c.z; r[dr][11] = c.w;
                    r[dr][12] = d.x; r[dr][13] = d.y;
                }
                #pragma unroll
                for (int k = 0; k < 9; ++k) {
                    const int ky = k / 3, kx = k % 3;
                    float w = w2s[(ic * 9 + k) * 16 + oc];   // 16 banks, 4-way bcast
                    #pragma unroll
                    for (int j = 0; j < 12; ++j)
                        acc[j] = fmaf(r[ky][j + kx], w, acc[j]);
                }
            }
        }
        // maxpool 2x2 (+bias,relu) + row-sum toward avg6x6, in-register.
        // row pairs (2p,2p+1) are 16 lanes apart within one wave.
        float bias = (t < 192) ? b2t[oc] : 0.f;
        float s = 0.f;
        #pragma unroll
        for (int c = 0; c < 6; ++c) {
            float m0 = fmaxf(acc[2 * c], acc[2 * c + 1]);
            float m1 = __shfl_down(m0, 16);
            s += fmaxf(fmaxf(m0, m1) + bias, 0.f);
        }
        s += __shfl_xor(s, 32);        // combine the wave's two even rows
        rowsum = s;
    }
    if (t < 192 && (t & 63) < 16)
        pool_part[(t >> 6) * 16 + (t & 15)] = rowsum;
    __syncthreads();

    if (t < 16)
        pool_s[t] = (pool_part[t] + pool_part[16 + t] + pool_part[32 + t]) * (1.f / 36.f);
    __syncthreads();

    // ---- fc1 (16->64) + relu + fc2 (64->4) in wave 0 ----
    if (t < 64) {
        const float4* f4 = (const float4*)(fw1 + t * 16);
        float4 wa = f4[0], wb = f4[1], wc = f4[2], wd = f4[3];
        float a1 = fb1[t];
        a1 = fmaf(pool_s[0],  wa.x, a1); a1 = fmaf(pool_s[1],  wa.y, a1);
        a1 = fmaf(pool_s[2],  wa.z, a1); a1 = fmaf(pool_s[3],  wa.w, a1);
        a1 = fmaf(pool_s[4],  wb.x, a1); a1 = fmaf(pool_s[5],  wb.y, a1);
        a1 = fmaf(pool_s[6],  wb.z, a1); a1 = fmaf(pool_s[7],  wb.w, a1);
        a1 = fmaf(pool_s[8],  wc.x, a1); a1 = fmaf(pool_s[9],  wc.y, a1);
        a1 = fmaf(pool_s[10], wc.z, a1); a1 = fmaf(pool_s[11], wc.w, a1);
        a1 = fmaf(pool_s[12], wd.x, a1); a1 = fmaf(pool_s[13], wd.y, a1);
        a1 = fmaf(pool_s[14], wd.z, a1); a1 = fmaf(pool_s[15], wd.w, a1);
        float f = fmaxf(a1, 0.f);
        float p0 = f * fw2[t];
        float p1 = f * fw2[64 + t];
        float p2 = f * fw2[128 + t];
        float p3 = f * fw2[192 + t];
        #pragma unroll
        for (int off = 32; off > 0; off >>= 1) {
            p0 += __shfl_down(p0, off);
            p1 += __shfl_down(p1, off);
            p2 += __shfl_down(p2, off);
            p3 += __shfl_down(p3, off);
        }
        if (t == 0) {
            ((float4*)out_pre)[b] = make_float4(p0 + fb2[0], p1 + fb2[1],
                                                p2 + fb2[2], p3 + fb2[3]);
        }
    }
}

// ====== K2: BN1 (grid sync #1, M build overlapped) + quantum + BN2 =========
__global__ __launch_bounds__(256) void k_tail(
    float* __restrict__ out_pre,
    const float* __restrict__ ng, const float* __restrict__ nb,
    const float* __restrict__ theta,
    const float* __restrict__ u_re, const float* __restrict__ u_im,
    const float* __restrict__ qg, const float* __restrict__ qb,
    float* __restrict__ bins1, float* __restrict__ bins2,
    unsigned int* __restrict__ counters)
{
    __shared__ float red[256];
    __shared__ float ss1[8], ss2[8];
    __shared__ float2 A[256], B[256], Ms[256];
    const int t = threadIdx.x;
    const int sidx = blockIdx.x * 256 + t;

    float4 o4 = ((const float4*)out_pre)[sidx];
    A[t] = make_float2(u_re[t], u_im[t]);
    float th0 = theta[0], th1 = theta[1], th2 = theta[2], th3 = theta[3];

    // ---- BN1 slice partials ----
    float vals[8] = {o4.x, o4.y, o4.z, o4.w,
                     o4.x * o4.x, o4.y * o4.y, o4.z * o4.z, o4.w * o4.w};
    #pragma unroll
    for (int off = 32; off > 0; off >>= 1)
        #pragma unroll
        for (int k = 0; k < 8; ++k) vals[k] += __shfl_down(vals[k], off);
    if ((t & 63) == 0) {
        int wid = t >> 6;
        #pragma unroll
        for (int k = 0; k < 8; ++k) red[wid * 8 + k] = vals[k];
    }
    __syncthreads();
    if (t < 8) {
        float s = red[t] + red[8 + t] + red[16 + t] + red[24 + t];
        __hip_atomic_store(&bins1[blockIdx.x * 8 + t], s,
                           __ATOMIC_RELEASE, __HIP_MEMORY_SCOPE_AGENT);
    }
    __syncthreads();
    if (t == 0) { __threadfence(); atomicAdd(&counters[0], 1u); }

    // ---- build fused M while other blocks publish (overlaps the wait) ----
    __syncthreads();
    float c0 = cosf(0.5f * th0), s0 = sinf(0.5f * th0);
    apply_1q(A, B, t, make_float2(c0, 0), make_float2(0, -s0),
                      make_float2(0, -s0), make_float2(c0, 0), 3);   // RX wire0
    __syncthreads();
    float c1 = cosf(0.5f * th1), s1 = sinf(0.5f * th1);
    apply_1q(B, A, t, make_float2(c1, 0), make_float2(-s1, 0),
                      make_float2(s1, 0), make_float2(c1, 0), 2);    // RY wire1
    __syncthreads();
    float c2 = cosf(0.5f * th2), s2 = sinf(0.5f * th2);
    apply_1q(A, B, t, make_float2(c2, -s2), make_float2(0, 0),
                      make_float2(0, 0), make_float2(c2, s2), 1);    // RZ wire2
    __syncthreads();
    float c3 = cosf(0.5f * th3), s3 = sinf(0.5f * th3);
    apply_ctrl(B, A, t, make_float2(c3, 0), make_float2(0, -s3),
                        make_float2(0, -s3), make_float2(c3, 0), 3, 0); // CRX w0->w3
    __syncthreads();
    const float hh = 0.70710678118654752440f;
    apply_1q(A, B, t, make_float2(hh, 0), make_float2(hh, 0),
                      make_float2(hh, 0), make_float2(-hh, 0), 0);   // H wire3
    __syncthreads();
    apply_1q(B, A, t, make_float2(0.5f, 0.5f), make_float2(0.5f, -0.5f),
                      make_float2(0.5f, -0.5f), make_float2(0.5f, 0.5f), 1); // SX wire2
    __syncthreads();
    apply_ctrl(A, B, t, make_float2(0, 0), make_float2(1, 0),
                        make_float2(1, 0), make_float2(0, 0), 0, 3); // CX w3->w0
    __syncthreads();
    Ms[t] = B[t];

    // ---- grid sync #1, then BN1 stats ----
    if (t == 0) {
        while (__hip_atomic_load(&counters[0], __ATOMIC_ACQUIRE,
                                 __HIP_MEMORY_SCOPE_AGENT) < 32u)
            __builtin_amdgcn_s_sleep(4);
    }
    __syncthreads();
    red[t] = bins1[t];
    __syncthreads();
    if (t < 8) {
        float s = 0.f;
        for (int bb = 0; bb < 32; ++bb) s += red[bb * 8 + t];
        red[t] = s;
    }
    if (t < 4) {
        float mean = red[t] * (1.f / 8192.f);
        float var = red[4 + t] * (1.f / 8192.f) - mean * mean;
        float sc = ng[t] * rsqrtf(var + 1e-5f);
        ss1[t] = sc;
        ss1[4 + t] = nb[t] - mean * sc;
    }
    __syncthreads();

    // ---- quantum: BN1 -> encoder product state -> M*psi -> <Z_w> ----
    float a[4];
    a[0] = fmaf(ss1[0], o4.x, ss1[4]);
    a[1] = fmaf(ss1[1], o4.y, ss1[5]);
    a[2] = fmaf(ss1[2], o4.z, ss1[6]);
    a[3] = fmaf(ss1[3], o4.w, ss1[7]);
    float2 v[4][2];
    #pragma unroll
    for (int w = 0; w < 4; ++w) {
        float s, c;
        __sincosf(0.5f * a[w], &s, &c);
        float2 v0 = make_float2(c * c, -c * s);
        float2 v1 = make_float2(s * c, s * s);
        float2 n0 = make_float2(c * v0.x + s * v1.y, c * v0.y - s * v1.x);
        float2 n1 = make_float2(s * v0.y + c * v1.x, -s * v0.x + c * v1.y);
        v[w][0] = make_float2(c * n0.x - s * n1.x, c * n0.y - s * n1.y);
        v[w][1] = make_float2(s * n0.x + c * n1.x, s * n0.y + c * n1.y);
    }
    float2 st[16];
    #pragma unroll
    for (int idx = 0; idx < 16; ++idx) {
        float2 p = cmul(v[0][(idx >> 3) & 1], v[1][(idx >> 2) & 1]);
        p = cmul(p, v[2][(idx >> 1) & 1]);
        st[idx] = cmul(p, v[3][idx & 1]);
    }
    float q[4] = {0.f, 0.f, 0.f, 0.f};
    #pragma unroll
    for (int j = 0; j < 16; ++j) {
        float2 acc = make_float2(0.f, 0.f);
        #pragma unroll
        for (int i = 0; i < 16; ++i) {
            float2 mm = Ms[j * 16 + i];
            acc.x = fmaf(mm.x, st[i].x, acc.x);
            acc.x = fmaf(-mm.y, st[i].y, acc.x);
            acc.y = fmaf(mm.x, st[i].y, acc.y);
            acc.y = fmaf(mm.y, st[i].x, acc.y);
        }
        float pr = acc.x * acc.x + acc.y * acc.y;
        q[0] += ((j >> 3) & 1) ? -pr : pr;
        q[1] += ((j >> 2) & 1) ? -pr : pr;
        q[2] += ((j >> 1) & 1) ? -pr : pr;
        q[3] += (j & 1) ? -pr : pr;
    }

    // ---- BN2 partials + grid sync #2 ----
    float vals2[8] = {q[0], q[1], q[2], q[3],
                      q[0] * q[0], q[1] * q[1], q[2] * q[2], q[3] * q[3]};
    #pragma unroll
    for (int off = 32; off > 0; off >>= 1)
        #pragma unroll
        for (int k = 0; k < 8; ++k) vals2[k] += __shfl_down(vals2[k], off);
    __syncthreads();                       // red free for reuse
    if ((t & 63) == 0) {
        int wid = t >> 6;
        #pragma unroll
        for (int k = 0; k < 8; ++k) red[wid * 8 + k] = vals2[k];
    }
    __syncthreads();
    if (t < 8) {
        float s = red[t] + red[8 + t] + red[16 + t] + red[24 + t];
        __hip_atomic_store(&bins2[blockIdx.x * 8 + t], s,
                           __ATOMIC_RELEASE, __HIP_MEMORY_SCOPE_AGENT);
    }
    __syncthreads();
    if (t == 0) {
        __threadfence();
        atomicAdd(&counters[1], 1u);
        while (__hip_atomic_load(&counters[1], __ATOMIC_ACQUIRE,
                                 __HIP_MEMORY_SCOPE_AGENT) < 32u)
            __builtin_amdgcn_s_sleep(4);
    }
    __syncthreads();
    red[t] = bins2[t];
    __syncthreads();
    if (t < 8) {
        float s = 0.f;
        for (int bb = 0; bb < 32; ++bb) s += red[bb * 8 + t];
        red[t] = s;
    }
    if (t < 4) {
        float m2 = red[t] * (1.f / 8192.f);
        float v2 = red[4 + t] * (1.f / 8192.f) - m2 * m2;
        float sc = qg[t] * rsqrtf(v2 + 1e-5f);
        ss2[t] = sc;
        ss2[4 + t] = qb[t] - m2 * sc;
    }
    __syncthreads();

    // ---- final combine ----
    float4 r;
    r.x = a[0] + fmaf(ss2[0], q[0], ss2[4]);
    r.y = a[1] + fmaf(ss2[1], q[1], ss2[5]);
    r.z = a[2] + fmaf(ss2[2], q[2], ss2[6]);
    r.w = a[3] + fmaf(ss2[3], q[3], ss2[7]);
    ((float4*)out_pre)[sidx] = r;
}

// ===========================================================================
extern "C" void kernel_launch(void* const* d_in, const int* in_sizes, int n_in,
                              void* d_out, int out_size, void* d_ws, size_t ws_size,
                              hipStream_t stream)
{
    const float* x     = (const float*)d_in[0];
    const float* w1    = (const float*)d_in[1];
    const float* b1    = (const float*)d_in[2];
    const float* w2    = (const float*)d_in[3];
    const float* b2    = (const float*)d_in[4];
    const float* fw1   = (const float*)d_in[5];
    const float* fb1   = (const float*)d_in[6];
    const float* fw2   = (const float*)d_in[7];
    const float* fb2   = (const float*)d_in[8];
    const float* ng    = (const float*)d_in[9];
    const float* nb    = (const float*)d_in[10];
    const float* theta = (const float*)d_in[11];
    const float* ure   = (const float*)d_in[12];
    const float* uim   = (const float*)d_in[13];
    const float* qg    = (const float*)d_in[14];
    const float* qb    = (const float*)d_in[15];

    float* ws = (float*)d_ws;
    unsigned int* counters = (unsigned int*)d_ws;   // [2]
    float* bins1 = ws + 16;                         // 256 floats
    float* bins2 = ws + 16 + 256;                   // 256 floats
    float* out_pre = (float*)d_out;

    k_cnn<<<8192, 256, 0, stream>>>(x, w1, b1, w2, b2, fw1, fb1, fw2, fb2,
                                    out_pre, counters);
    k_tail<<<32, 256, 0, stream>>>(out_pre, ng, nb, theta, ure, uim, qg, qb,
                                   bins1, bins2, counters);
}

// Round 8
// 163.407 us; speedup vs baseline: 1.3860x; 1.0068x over previous
//
#include <hip/hip_runtime.h>
#include <math.h>

// ---------------------------------------------------------------------------
// EstimatorQNNHybrid, round 8: conv2 via FP16 MFMA (16x16x32_f16).
// R7 structure (validated: bf16 run hit exactly the bf16 precision floor,
// absmax 0.109 vs thr 0.106) with fp16 operands: eps 2^-11 vs 2^-9 -> ~4x
// accuracy headroom. Same fragment layouts / LDS plan / 27 MFMA.
//  k_cnn : conv1 fp32 vector -> h1s; im2col A (fp16, K-order (ky,kx,ic),
//          row 208B) in LDS; 27 MFMA over waves 0-2; C -> h2p (aliases A);
//          pool + fc1 + fc2. Weights staged fp16 by wave 3 during conv1.
//  k_tail: unchanged (BN1 + M build + quantum + BN2, 2 spin grid-syncs).
// LDS: A 29952B (aliases xs/h2p) | h1s @30208 | Bt @39168 = 42.5 KB.
// ---------------------------------------------------------------------------

#define XS_S 34      // 29x34 padded input (row0/col0 pad), lives inside A
#define H1_S 20      // 14x20 padded conv1-pooled planes
#define H1_P 280
#define A_OFF   0        // 144 rows x 208 B (104 f16)
#define H1_OFF  30208    // 8*280 f32 = 8960 B
#define BT_OFF  39168    // 16 rows x 208 B
#define SMEM_SZ 42496

typedef _Float16 half8 __attribute__((ext_vector_type(8)));
typedef float v4f __attribute__((ext_vector_type(4)));

// pack two f32 -> two f16 (RNE via v_cvt_f16_f32)
__device__ __forceinline__ unsigned pkf16(float a, float b) {
    _Float16 ha = (_Float16)a, hb = (_Float16)b;
    unsigned short ua = __builtin_bit_cast(unsigned short, ha);
    unsigned short ub = __builtin_bit_cast(unsigned short, hb);
    return ((unsigned)ub << 16) | (unsigned)ua;
}

__device__ __forceinline__ float2 cmul(float2 a, float2 b) {
    return make_float2(a.x * b.x - a.y * b.y, a.x * b.y + a.y * b.x);
}
__device__ __forceinline__ float2 cadd(float2 a, float2 b) {
    return make_float2(a.x + b.x, a.y + b.y);
}

__device__ __forceinline__ void apply_1q(const float2* src, float2* dst, int t,
                                         float2 g00, float2 g01, float2 g10, float2 g11, int p)
{
    int j = t >> 4, i = t & 15;
    int jb = (j >> p) & 1;
    int k0 = j & ~(1 << p);
    int k1 = j | (1 << p);
    float2 a0 = src[k0 * 16 + i], a1 = src[k1 * 16 + i];
    float2 r = jb ? cadd(cmul(g10, a0), cmul(g11, a1))
                  : cadd(cmul(g00, a0), cmul(g01, a1));
    dst[j * 16 + i] = r;
}

__device__ __forceinline__ void apply_ctrl(const float2* src, float2* dst, int t,
                                           float2 g00, float2 g01, float2 g10, float2 g11,
                                           int pc, int pt)
{
    int j = t >> 4, i = t & 15;
    float2 r;
    if (((j >> pc) & 1) == 0) {
        r = src[j * 16 + i];
    } else {
        int jb = (j >> pt) & 1;
        int k0 = j & ~(1 << pt);
        int k1 = j | (1 << pt);
        float2 a0 = src[k0 * 16 + i], a1 = src[k1 * 16 + i];
        r = jb ? cadd(cmul(g10, a0), cmul(g11, a1))
               : cadd(cmul(g00, a0), cmul(g01, a1));
    }
    dst[j * 16 + i] = r;
}

// ========================= K1: fused CNN per sample =========================
__global__ __launch_bounds__(256, 3) void k_cnn(
    const float* __restrict__ x,
    const float* __restrict__ w1, const float* __restrict__ b1,
    const float* __restrict__ w2, const float* __restrict__ b2,
    const float* __restrict__ fw1, const float* __restrict__ fb1,
    const float* __restrict__ fw2, const float* __restrict__ fb2,
    float* __restrict__ out_pre, unsigned int* __restrict__ counters)
{
    __shared__ __align__(16) char smem[SMEM_SZ];
    __shared__ float w1t[72];
    __shared__ float b1t[8], b2t[16];
    __shared__ float pool_s[16];

    const int t = threadIdx.x;
    const int b = blockIdx.x;
    const float* xg = x + b * 784;
    float* xs  = (float*)smem;                    // phase 1 only (inside A)
    float* h1f = (float*)(smem + H1_OFF);

    // ---- phase A: pads + interior + small weights + Bt pad (disjoint) ----
    if (b == 0 && t < 2) counters[t] = 0u;
    if (t < 57) {
        if (t < 29) xs[t] = 0.f;
        else        xs[(t - 28) * XS_S] = 0.f;
    }
    if (t < 216) {                                // h1 pads: row0 + col0 per plane
        int pl = t / 27, r = t % 27;
        if (r < 14) h1f[pl * H1_P + r] = 0.f;
        else        h1f[pl * H1_P + (r - 13) * H1_S] = 0.f;
    }
    if (t >= 64 && t < 136) {                     // w1 [c][k] -> [k][8c]
        int i = t - 64;
        w1t[(i % 9) * 8 + (i / 9)] = w1[i];
    }
    if (t < 196) {                                // interior, 196 float4
        float4 v = ((const float4*)xg)[t];
        int p = t * 4;
        int yy = p / 28, xx = p % 28;
        int base = (yy + 1) * XS_S + xx + 1;
        xs[base] = v.x; xs[base + 1] = v.y; xs[base + 2] = v.z; xs[base + 3] = v.w;
    }
    if (t < 48) {                                 // Bt pad kk 72..95 = 0
        int oc = t / 3, part = t % 3;
        *(uint4*)(smem + BT_OFF + oc * 208 + 144 + part * 16) = make_uint4(0, 0, 0, 0);
    }
    if (t < 8)  b1t[t] = b1[t];
    if (t < 16) b2t[t] = b2[t];
    __syncthreads();

    // ---- conv1 (1->8)+relu+pool: 169 lanes; wave 3 stages Bt (fp16 RNE) ----
    if (t < 169) {
        const int py = t / 13, px = t % 13;
        float patch[4][4];
        #pragma unroll
        for (int dr = 0; dr < 4; ++dr) {
            int base = (2 * py + dr) * XS_S + 2 * px;
            float2 a = *(const float2*)&xs[base];
            float2 c = *(const float2*)&xs[base + 2];
            patch[dr][0] = a.x; patch[dr][1] = a.y;
            patch[dr][2] = c.x; patch[dr][3] = c.y;
        }
        float acc[8][2][2];
        #pragma unroll
        for (int c = 0; c < 8; ++c)
            #pragma unroll
            for (int dy = 0; dy < 2; ++dy)
                #pragma unroll
                for (int dx = 0; dx < 2; ++dx) acc[c][dy][dx] = 0.f;
        #pragma unroll
        for (int k = 0; k < 9; ++k) {
            const int ky = k / 3, kx = k % 3;
            float4 wA = *(const float4*)&w1t[k * 8];
            float4 wB = *(const float4*)&w1t[k * 8 + 4];
            float w8[8] = {wA.x, wA.y, wA.z, wA.w, wB.x, wB.y, wB.z, wB.w};
            #pragma unroll
            for (int c = 0; c < 8; ++c)
                #pragma unroll
                for (int dy = 0; dy < 2; ++dy)
                    #pragma unroll
                    for (int dx = 0; dx < 2; ++dx)
                        acc[c][dy][dx] = fmaf(patch[dy + ky][dx + kx], w8[c], acc[c][dy][dx]);
        }
        #pragma unroll
        for (int c = 0; c < 8; ++c) {
            float m = fmaxf(fmaxf(acc[c][0][0], acc[c][0][1]),
                            fmaxf(acc[c][1][0], acc[c][1][1])) + b1t[c];
            h1f[c * H1_P + (py + 1) * H1_S + (px + 1)] = fmaxf(m, 0.f);
        }
    } else if (t >= 192) {
        // wave 3: Bt[oc][kk=(ky*3+kx)*8+ic] <- f16(w2[oc][ic][k])
        unsigned short* bt = (unsigned short*)(smem + BT_OFF);
        for (int i = t - 192; i < 1152; i += 64) {
            int oc = i / 72, r = i % 72, ic = r / 9, kidx = r % 9;
            _Float16 h = (_Float16)w2[i];
            bt[oc * 104 + kidx * 8 + ic] = __builtin_bit_cast(unsigned short, h);
        }
    }
    __syncthreads();

    // ---- im2col A staging (fp16): 144 threads = pos; 9 rounds + pad -------
    if (t < 144) {
        const int y = t / 12, xx2 = t % 12;
        #pragma unroll
        for (int kidx = 0; kidx < 9; ++kidx) {
            const int ky = kidx / 3, kx = kidx % 3;
            const int hoff = (y + ky) * H1_S + (xx2 + kx);
            float v0 = h1f[0 * H1_P + hoff];
            float v1 = h1f[1 * H1_P + hoff];
            float v2 = h1f[2 * H1_P + hoff];
            float v3 = h1f[3 * H1_P + hoff];
            float v4 = h1f[4 * H1_P + hoff];
            float v5 = h1f[5 * H1_P + hoff];
            float v6 = h1f[6 * H1_P + hoff];
            float v7 = h1f[7 * H1_P + hoff];
            uint4 wv = make_uint4(pkf16(v0, v1), pkf16(v2, v3),
                                  pkf16(v4, v5), pkf16(v6, v7));
            *(uint4*)(smem + A_OFF + t * 208 + kidx * 16) = wv;
        }
        uint4 z = make_uint4(0, 0, 0, 0);          // A pad kk 72..95
        *(uint4*)(smem + A_OFF + t * 208 + 144) = z;
        *(uint4*)(smem + A_OFF + t * 208 + 160) = z;
        *(uint4*)(smem + A_OFF + t * 208 + 176) = z;
    }
    __syncthreads();

    // ---- conv2 = 27x mfma_f32_16x16x32_f16 over waves 0-2 -----------------
    const int wv_id = t >> 6, lane = t & 63, quad = lane >> 4, n = lane & 15;
    v4f acc0 = {0.f, 0.f, 0.f, 0.f}, acc1 = acc0, acc2 = acc0;
    if (wv_id < 3) {
        half8 bfr[3];
        #pragma unroll
        for (int kc = 0; kc < 3; ++kc)
            bfr[kc] = *(const half8*)(smem + BT_OFF + n * 208 + kc * 64 + quad * 16);
        const int arow0 = (wv_id * 3) * 16 + n;
        #pragma unroll
        for (int kc = 0; kc < 3; ++kc) {
            half8 af = *(const half8*)(smem + A_OFF + arow0 * 208 + kc * 64 + quad * 16);
            acc0 = __builtin_amdgcn_mfma_f32_16x16x32_f16(af, bfr[kc], acc0, 0, 0, 0);
        }
        #pragma unroll
        for (int kc = 0; kc < 3; ++kc) {
            half8 af = *(const half8*)(smem + A_OFF + (arow0 + 16) * 208 + kc * 64 + quad * 16);
            acc1 = __builtin_amdgcn_mfma_f32_16x16x32_f16(af, bfr[kc], acc1, 0, 0, 0);
        }
        #pragma unroll
        for (int kc = 0; kc < 3; ++kc) {
            half8 af = *(const half8*)(smem + A_OFF + (arow0 + 32) * 208 + kc * 64 + quad * 16);
            acc2 = __builtin_amdgcn_mfma_f32_16x16x32_f16(af, bfr[kc], acc2, 0, 0, 0);
        }
    }
    __syncthreads();                               // A dead -> reuse as h2p

    float* h2p = (float*)smem;                     // [144 pos][16 oc]
    if (wv_id < 3) {
        const int posb = (wv_id * 3) * 16 + quad * 4;
        #pragma unroll
        for (int r = 0; r < 4; ++r) h2p[(posb + r) * 16 + n]      = acc0[r];
        #pragma unroll
        for (int r = 0; r < 4; ++r) h2p[(posb + 16 + r) * 16 + n] = acc1[r];
        #pragma unroll
        for (int r = 0; r < 4; ++r) h2p[(posb + 32 + r) * 16 + n] = acc2[r];
    }
    __syncthreads();

    // ---- maxpool(2x2) + bias + relu + avg 6x6: 64 lanes --------------------
    if (t < 64) {
        const int oc = t >> 2, q = t & 3;
        const float bias = b2t[oc];
        float s = 0.f;
        #pragma unroll
        for (int r = 0; r < 9; ++r) {
            int idx = q * 9 + r;
            int pr = idx / 6, pc = idx % 6;
            int p00 = (2 * pr * 12 + 2 * pc) * 16 + oc;
            float m = fmaxf(fmaxf(h2p[p00], h2p[p00 + 16]),
                            fmaxf(h2p[p00 + 192], h2p[p00 + 208]));
            s += fmaxf(m + bias, 0.f);
        }
        s += __shfl_xor(s, 1);
        s += __shfl_xor(s, 2);
        if (q == 0) pool_s[oc] = s * (1.f / 36.f);
    }
    __syncthreads();

    // ---- fc1 (16->64) + relu + fc2 (64->4) in wave 0 -----------------------
    if (t < 64) {
        const float4* f4 = (const float4*)(fw1 + t * 16);
        float4 wa = f4[0], wb = f4[1], wc = f4[2], wd = f4[3];
        float a1 = fb1[t];
        a1 = fmaf(pool_s[0],  wa.x, a1); a1 = fmaf(pool_s[1],  wa.y, a1);
        a1 = fmaf(pool_s[2],  wa.z, a1); a1 = fmaf(pool_s[3],  wa.w, a1);
        a1 = fmaf(pool_s[4],  wb.x, a1); a1 = fmaf(pool_s[5],  wb.y, a1);
        a1 = fmaf(pool_s[6],  wb.z, a1); a1 = fmaf(pool_s[7],  wb.w, a1);
        a1 = fmaf(pool_s[8],  wc.x, a1); a1 = fmaf(pool_s[9],  wc.y, a1);
        a1 = fmaf(pool_s[10], wc.z, a1); a1 = fmaf(pool_s[11], wc.w, a1);
        a1 = fmaf(pool_s[12], wd.x, a1); a1 = fmaf(pool_s[13], wd.y, a1);
        a1 = fmaf(pool_s[14], wd.z, a1); a1 = fmaf(pool_s[15], wd.w, a1);
        float f = fmaxf(a1, 0.f);
        float p0 = f * fw2[t];
        float p1 = f * fw2[64 + t];
        float p2 = f * fw2[128 + t];
        float p3 = f * fw2[192 + t];
        #pragma unroll
        for (int off = 32; off > 0; off >>= 1) {
            p0 += __shfl_down(p0, off);
            p1 += __shfl_down(p1, off);
            p2 += __shfl_down(p2, off);
            p3 += __shfl_down(p3, off);
        }
        if (t == 0) {
            ((float4*)out_pre)[b] = make_float4(p0 + fb2[0], p1 + fb2[1],
                                                p2 + fb2[2], p3 + fb2[3]);
        }
    }
}

// ====== K2: BN1 (grid sync #1, M build overlapped) + quantum + BN2 =========
__global__ __launch_bounds__(256) void k_tail(
    float* __restrict__ out_pre,
    const float* __restrict__ ng, const float* __restrict__ nb,
    const float* __restrict__ theta,
    const float* __restrict__ u_re, const float* __restrict__ u_im,
    const float* __restrict__ qg, const float* __restrict__ qb,
    float* __restrict__ bins1, float* __restrict__ bins2,
    unsigned int* __restrict__ counters)
{
    __shared__ float red[256];
    __shared__ float ss1[8], ss2[8];
    __shared__ float2 A[256], B[256], Ms[256];
    const int t = threadIdx.x;
    const int sidx = blockIdx.x * 256 + t;

    float4 o4 = ((const float4*)out_pre)[sidx];
    A[t] = make_float2(u_re[t], u_im[t]);
    float th0 = theta[0], th1 = theta[1], th2 = theta[2], th3 = theta[3];

    float vals[8] = {o4.x, o4.y, o4.z, o4.w,
                     o4.x * o4.x, o4.y * o4.y, o4.z * o4.z, o4.w * o4.w};
    #pragma unroll
    for (int off = 32; off > 0; off >>= 1)
        #pragma unroll
        for (int k = 0; k < 8; ++k) vals[k] += __shfl_down(vals[k], off);
    if ((t & 63) == 0) {
        int wid = t >> 6;
        #pragma unroll
        for (int k = 0; k < 8; ++k) red[wid * 8 + k] = vals[k];
    }
    __syncthreads();
    if (t < 8) {
        float s = red[t] + red[8 + t] + red[16 + t] + red[24 + t];
        __hip_atomic_store(&bins1[blockIdx.x * 8 + t], s,
                           __ATOMIC_RELEASE, __HIP_MEMORY_SCOPE_AGENT);
    }
    __syncthreads();
    if (t == 0) { __threadfence(); atomicAdd(&counters[0], 1u); }

    __syncthreads();
    float c0 = cosf(0.5f * th0), s0 = sinf(0.5f * th0);
    apply_1q(A, B, t, make_float2(c0, 0), make_float2(0, -s0),
                      make_float2(0, -s0), make_float2(c0, 0), 3);   // RX wire0
    __syncthreads();
    float c1 = cosf(0.5f * th1), s1 = sinf(0.5f * th1);
    apply_1q(B, A, t, make_float2(c1, 0), make_float2(-s1, 0),
                      make_float2(s1, 0), make_float2(c1, 0), 2);    // RY wire1
    __syncthreads();
    float c2 = cosf(0.5f * th2), s2 = sinf(0.5f * th2);
    apply_1q(A, B, t, make_float2(c2, -s2), make_float2(0, 0),
                      make_float2(0, 0), make_float2(c2, s2), 1);    // RZ wire2
    __syncthreads();
    float c3 = cosf(0.5f * th3), s3 = sinf(0.5f * th3);
    apply_ctrl(B, A, t, make_float2(c3, 0), make_float2(0, -s3),
                        make_float2(0, -s3), make_float2(c3, 0), 3, 0); // CRX w0->w3
    __syncthreads();
    const float hh = 0.70710678118654752440f;
    apply_1q(A, B, t, make_float2(hh, 0), make_float2(hh, 0),
                      make_float2(hh, 0), make_float2(-hh, 0), 0);   // H wire3
    __syncthreads();
    apply_1q(B, A, t, make_float2(0.5f, 0.5f), make_float2(0.5f, -0.5f),
                      make_float2(0.5f, -0.5f), make_float2(0.5f, 0.5f), 1); // SX wire2
    __syncthreads();
    apply_ctrl(A, B, t, make_float2(0, 0), make_float2(1, 0),
                        make_float2(1, 0), make_float2(0, 0), 0, 3); // CX w3->w0
    __syncthreads();
    Ms[t] = B[t];

    if (t == 0) {
        while (__hip_atomic_load(&counters[0], __ATOMIC_ACQUIRE,
                                 __HIP_MEMORY_SCOPE_AGENT) < 32u)
            __builtin_amdgcn_s_sleep(4);
    }
    __syncthreads();
    red[t] = bins1[t];
    __syncthreads();
    if (t < 8) {
        float s = 0.f;
        for (int bb = 0; bb < 32; ++bb) s += red[bb * 8 + t];
        red[t] = s;
    }
    if (t < 4) {
        float mean = red[t] * (1.f / 8192.f);
        float var = red[4 + t] * (1.f / 8192.f) - mean * mean;
        float sc = ng[t] * rsqrtf(var + 1e-5f);
        ss1[t] = sc;
        ss1[4 + t] = nb[t] - mean * sc;
    }
    __syncthreads();

    float a[4];
    a[0] = fmaf(ss1[0], o4.x, ss1[4]);
    a[1] = fmaf(ss1[1], o4.y, ss1[5]);
    a[2] = fmaf(ss1[2], o4.z, ss1[6]);
    a[3] = fmaf(ss1[3], o4.w, ss1[7]);
    float2 v[4][2];
    #pragma unroll
    for (int w = 0; w < 4; ++w) {
        float s, c;
        __sincosf(0.5f * a[w], &s, &c);
        float2 v0 = make_float2(c * c, -c * s);
        float2 v1 = make_float2(s * c, s * s);
        float2 n0 = make_float2(c * v0.x + s * v1.y, c * v0.y - s * v1.x);
        float2 n1 = make_float2(s * v0.y + c * v1.x, -s * v0.x + c * v1.y);
        v[w][0] = make_float2(c * n0.x - s * n1.x, c * n0.y - s * n1.y);
        v[w][1] = make_float2(s * n0.x + c * n1.x, s * n0.y + c * n1.y);
    }
    float2 st[16];
    #pragma unroll
    for (int idx = 0; idx < 16; ++idx) {
        float2 p = cmul(v[0][(idx >> 3) & 1], v[1][(idx >> 2) & 1]);
        p = cmul(p, v[2][(idx >> 1) & 1]);
        st[idx] = cmul(p, v[3][idx & 1]);
    }
    float q[4] = {0.f, 0.f, 0.f, 0.f};
    #pragma unroll
    for (int j = 0; j < 16; ++j) {
        float2 acc = make_float2(0.f, 0.f);
        #pragma unroll
        for (int i = 0; i < 16; ++i) {
            float2 mm = Ms[j * 16 + i];
            acc.x = fmaf(mm.x, st[i].x, acc.x);
            acc.x = fmaf(-mm.y, st[i].y, acc.x);
            acc.y = fmaf(mm.x, st[i].y, acc.y);
            acc.y = fmaf(mm.y, st[i].x, acc.y);
        }
        float pr = acc.x * acc.x + acc.y * acc.y;
        q[0] += ((j >> 3) & 1) ? -pr : pr;
        q[1] += ((j >> 2) & 1) ? -pr : pr;
        q[2] += ((j >> 1) & 1) ? -pr : pr;
        q[3] += (j & 1) ? -pr : pr;
    }

    float vals2[8] = {q[0], q[1], q[2], q[3],
                      q[0] * q[0], q[1] * q[1], q[2] * q[2], q[3] * q[3]};
    #pragma unroll
    for (int off = 32; off > 0; off >>= 1)
        #pragma unroll
        for (int k = 0; k < 8; ++k) vals2[k] += __shfl_down(vals2[k], off);
    __syncthreads();
    if ((t & 63) == 0) {
        int wid = t >> 6;
        #pragma unroll
        for (int k = 0; k < 8; ++k) red[wid * 8 + k] = vals2[k];
    }
    __syncthreads();
    if (t < 8) {
        float s = red[t] + red[8 + t] + red[16 + t] + red[24 + t];
        __hip_atomic_store(&bins2[blockIdx.x * 8 + t], s,
                           __ATOMIC_RELEASE, __HIP_MEMORY_SCOPE_AGENT);
    }
    __syncthreads();
    if (t == 0) {
        __threadfence();
        atomicAdd(&counters[1], 1u);
        while (__hip_atomic_load(&counters[1], __ATOMIC_ACQUIRE,
                                 __HIP_MEMORY_SCOPE_AGENT) < 32u)
            __builtin_amdgcn_s_sleep(4);
    }
    __syncthreads();
    red[t] = bins2[t];
    __syncthreads();
    if (t < 8) {
        float s = 0.f;
        for (int bb = 0; bb < 32; ++bb) s += red[bb * 8 + t];
        red[t] = s;
    }
    if (t < 4) {
        float m2 = red[t] * (1.f / 8192.f);
        float v2 = red[4 + t] * (1.f / 8192.f) - m2 * m2;
        float sc = qg[t] * rsqrtf(v2 + 1e-5f);
        ss2[t] = sc;
        ss2[4 + t] = qb[t] - m2 * sc;
    }
    __syncthreads();

    float4 r;
    r.x = a[0] + fmaf(ss2[0], q[0], ss2[4]);
    r.y = a[1] + fmaf(ss2[1], q[1], ss2[5]);
    r.z = a[2] + fmaf(ss2[2], q[2], ss2[6]);
    r.w = a[3] + fmaf(ss2[3], q[3], ss2[7]);
    ((float4*)out_pre)[sidx] = r;
}

// ===========================================================================
extern "C" void kernel_launch(void* const* d_in, const int* in_sizes, int n_in,
                              void* d_out, int out_size, void* d_ws, size_t ws_size,
                              hipStream_t stream)
{
    const float* x     = (const float*)d_in[0];
    const float* w1    = (const float*)d_in[1];
    const float* b1    = (const float*)d_in[2];
    const float* w2    = (const float*)d_in[3];
    const float* b2    = (const float*)d_in[4];
    const float* fw1   = (const float*)d_in[5];
    const float* fb1   = (const float*)d_in[6];
    const float* fw2   = (const float*)d_in[7];
    const float* fb2   = (const float*)d_in[8];
    const float* ng    = (const float*)d_in[9];
    const float* nb    = (const float*)d_in[10];
    const float* theta = (const float*)d_in[11];
    const float* ure   = (const float*)d_in[12];
    const float* uim   = (const float*)d_in[13];
    const float* qg    = (const float*)d_in[14];
    const float* qb    = (const float*)d_in[15];

    float* ws = (float*)d_ws;
    unsigned int* counters = (unsigned int*)d_ws;   // [2]
    float* bins1 = ws + 16;                         // 256 floats
    float* bins2 = ws + 16 + 256;                   // 256 floats
    float* out_pre = (float*)d_out;

    k_cnn<<<8192, 256, 0, stream>>>(x, w1, b1, w2, b2, fw1, fb1, fw2, fb2,
                                    out_pre, counters);
    k_tail<<<32, 256, 0, stream>>>(out_pre, ng, nb, theta, ure, uim, qg, qb,
                                   bins1, bins2, counters);
}

// Round 9
// 132.435 us; speedup vs baseline: 1.7102x; 1.2339x over previous
//
#include <hip/hip_runtime.h>
#include <math.h>

// ---------------------------------------------------------------------------
// EstimatorQNNHybrid, round 9: register-built MFMA A-fragments (no im2col).
//  k_cnn : conv1 fp32 vector -> h1i = packed fp16 channel-pairs
//          [4 pair-planes][14][20] (u32). conv2 MFMA A-fragments gathered
//          directly: lane(quad,n) reads 4x ds_read_b32 (pairs 0..3) at
//          (y(m)+ky, x(m)+kx), kidx=kc*4+quad; kidx>=9 -> zero frag
//          (predicated, no stored pad). B from Bt[16][72 fp16] rows (144B),
//          same predication. Deletes 30KB A buffer + im2col phase + barrier.
//          LDS 43 -> 15.6KB -> 6 blocks/CU.
//  k_tail: unchanged (BN1 + M build + quantum + BN2, 2 spin grid-syncs).
// LDS: h2p/xs @0 (9216, aliased) | h1i @9216 (4480) | Bt @13696 (2304).
// ---------------------------------------------------------------------------

#define XS_S 34      // 29x34 padded fp32 input (row0/col0 pad), inside h2p
#define H1_S 20      // u32 row stride of pair-planes
#define H1_P 280     // u32 plane stride (14*20)
#define H1I_OFF 9216
#define BT_OFF  13696
#define SMEM_SZ 16000

typedef _Float16 half8 __attribute__((ext_vector_type(8)));
typedef float v4f __attribute__((ext_vector_type(4)));

// pack two f32 -> two f16 (RNE), low half = a
__device__ __forceinline__ unsigned pkf16(float a, float b) {
    _Float16 ha = (_Float16)a, hb = (_Float16)b;
    unsigned short ua = __builtin_bit_cast(unsigned short, ha);
    unsigned short ub = __builtin_bit_cast(unsigned short, hb);
    return ((unsigned)ub << 16) | (unsigned)ua;
}

__device__ __forceinline__ float2 cmul(float2 a, float2 b) {
    return make_float2(a.x * b.x - a.y * b.y, a.x * b.y + a.y * b.x);
}
__device__ __forceinline__ float2 cadd(float2 a, float2 b) {
    return make_float2(a.x + b.x, a.y + b.y);
}

__device__ __forceinline__ void apply_1q(const float2* src, float2* dst, int t,
                                         float2 g00, float2 g01, float2 g10, float2 g11, int p)
{
    int j = t >> 4, i = t & 15;
    int jb = (j >> p) & 1;
    int k0 = j & ~(1 << p);
    int k1 = j | (1 << p);
    float2 a0 = src[k0 * 16 + i], a1 = src[k1 * 16 + i];
    float2 r = jb ? cadd(cmul(g10, a0), cmul(g11, a1))
                  : cadd(cmul(g00, a0), cmul(g01, a1));
    dst[j * 16 + i] = r;
}

__device__ __forceinline__ void apply_ctrl(const float2* src, float2* dst, int t,
                                           float2 g00, float2 g01, float2 g10, float2 g11,
                                           int pc, int pt)
{
    int j = t >> 4, i = t & 15;
    float2 r;
    if (((j >> pc) & 1) == 0) {
        r = src[j * 16 + i];
    } else {
        int jb = (j >> pt) & 1;
        int k0 = j & ~(1 << pt);
        int k1 = j | (1 << pt);
        float2 a0 = src[k0 * 16 + i], a1 = src[k1 * 16 + i];
        r = jb ? cadd(cmul(g10, a0), cmul(g11, a1))
               : cadd(cmul(g00, a0), cmul(g01, a1));
    }
    dst[j * 16 + i] = r;
}

// ========================= K1: fused CNN per sample =========================
__global__ __launch_bounds__(256, 6) void k_cnn(
    const float* __restrict__ x,
    const float* __restrict__ w1, const float* __restrict__ b1,
    const float* __restrict__ w2, const float* __restrict__ b2,
    const float* __restrict__ fw1, const float* __restrict__ fb1,
    const float* __restrict__ fw2, const float* __restrict__ fb2,
    float* __restrict__ out_pre, unsigned int* __restrict__ counters)
{
    __shared__ __align__(16) char smem[SMEM_SZ];
    __shared__ float w1t[72];
    __shared__ float b1t[8], b2t[16];
    __shared__ float pool_s[16];

    const int t = threadIdx.x;
    const int b = blockIdx.x;
    const float* xg = x + b * 784;
    float* xs = (float*)smem;                          // conv1 input (dies after conv1)
    unsigned* h1u = (unsigned*)(smem + H1I_OFF);       // packed fp16 pairs

    // ---- phase A: pads + interior + small weights (disjoint writes) ----
    if (b == 0 && t < 2) counters[t] = 0u;
    if (t < 57) {
        if (t < 29) xs[t] = 0.f;
        else        xs[(t - 28) * XS_S] = 0.f;
    }
    if (t < 108) {                                 // h1i pads: row0(14)+col0(13) x 4 pairs
        int pl = t / 27, r = t % 27;
        if (r < 14) h1u[pl * H1_P + r] = 0u;
        else        h1u[pl * H1_P + (r - 13) * H1_S] = 0u;
    }
    if (t >= 64 && t < 136) {                      // w1 [c][k] -> [k][8c]
        int i = t - 64;
        w1t[(i % 9) * 8 + (i / 9)] = w1[i];
    }
    if (t < 196) {                                 // interior, 196 float4
        float4 v = ((const float4*)xg)[t];
        int p = t * 4;
        int yy = p / 28, xx = p % 28;
        int base = (yy + 1) * XS_S + xx + 1;
        xs[base] = v.x; xs[base + 1] = v.y; xs[base + 2] = v.z; xs[base + 3] = v.w;
    }
    if (t < 8)  b1t[t] = b1[t];
    if (t < 16) b2t[t] = b2[t];
    __syncthreads();

    // ---- conv1 (1->8)+relu+pool: 169 lanes -> packed fp16 pairs; wave3: Bt --
    if (t < 169) {
        const int py = t / 13, px = t % 13;
        float patch[4][4];
        #pragma unroll
        for (int dr = 0; dr < 4; ++dr) {
            int base = (2 * py + dr) * XS_S + 2 * px;
            float2 a = *(const float2*)&xs[base];
            float2 c = *(const float2*)&xs[base + 2];
            patch[dr][0] = a.x; patch[dr][1] = a.y;
            patch[dr][2] = c.x; patch[dr][3] = c.y;
        }
        float acc[8][2][2];
        #pragma unroll
        for (int c = 0; c < 8; ++c)
            #pragma unroll
            for (int dy = 0; dy < 2; ++dy)
                #pragma unroll
                for (int dx = 0; dx < 2; ++dx) acc[c][dy][dx] = 0.f;
        #pragma unroll
        for (int k = 0; k < 9; ++k) {
            const int ky = k / 3, kx = k % 3;
            float4 wA = *(const float4*)&w1t[k * 8];
            float4 wB = *(const float4*)&w1t[k * 8 + 4];
            float w8[8] = {wA.x, wA.y, wA.z, wA.w, wB.x, wB.y, wB.z, wB.w};
            #pragma unroll
            for (int c = 0; c < 8; ++c)
                #pragma unroll
                for (int dy = 0; dy < 2; ++dy)
                    #pragma unroll
                    for (int dx = 0; dx < 2; ++dx)
                        acc[c][dy][dx] = fmaf(patch[dy + ky][dx + kx], w8[c], acc[c][dy][dx]);
        }
        float v8[8];
        #pragma unroll
        for (int c = 0; c < 8; ++c) {
            float m = fmaxf(fmaxf(acc[c][0][0], acc[c][0][1]),
                            fmaxf(acc[c][1][0], acc[c][1][1])) + b1t[c];
            v8[c] = fmaxf(m, 0.f);
        }
        const int ha = (py + 1) * H1_S + (px + 1);
        h1u[ha]             = pkf16(v8[0], v8[1]);
        h1u[H1_P + ha]      = pkf16(v8[2], v8[3]);
        h1u[2 * H1_P + ha]  = pkf16(v8[4], v8[5]);
        h1u[3 * H1_P + ha]  = pkf16(v8[6], v8[7]);
    } else if (t >= 192) {
        // wave 3: Bt[oc][kidx*8+ic] <- f16(w2[oc][ic][kidx]), row 144B
        unsigned short* bt = (unsigned short*)(smem + BT_OFF);
        for (int i = t - 192; i < 1152; i += 64) {
            int oc = i / 72, r = i % 72, ic = r / 9, kidx = r % 9;
            _Float16 h = (_Float16)w2[i];
            bt[oc * 72 + kidx * 8 + ic] = __builtin_bit_cast(unsigned short, h);
        }
    }
    __syncthreads();

    // ---- conv2 = 9 MFMA/wave (waves 0-2), A-frags gathered from h1i --------
    const int wv_id = t >> 6, lane = t & 63, quad = lane >> 4, n = lane & 15;
    v4f acc0 = {0.f, 0.f, 0.f, 0.f}, acc1 = acc0, acc2 = acc0;
    if (wv_id < 3) {
        const half8 hz = {0, 0, 0, 0, 0, 0, 0, 0};
        half8 bfr[3];
        int koff[3];
        #pragma unroll
        for (int kc = 0; kc < 3; ++kc) {
            const int kidx = kc * 4 + quad;
            bfr[kc] = (kidx < 9)
                ? *(const half8*)(smem + BT_OFF + n * 144 + kc * 64 + quad * 16)
                : hz;
            koff[kc] = (kidx < 9) ? (kidx / 3) * H1_S + (kidx % 3) : 0;
        }
        #pragma unroll
        for (int g = 0; g < 3; ++g) {
            const int m = (wv_id * 3 + g) * 16 + n;           // pos 0..143
            const int y = m / 12, xx2 = m % 12;
            const int pbase = y * H1_S + xx2;
            v4f* accp = (g == 0) ? &acc0 : (g == 1) ? &acc1 : &acc2;
            #pragma unroll
            for (int kc = 0; kc < 3; ++kc) {
                const int kidx = kc * 4 + quad;
                half8 af;
                if (kidx < 9) {
                    const int a0 = pbase + koff[kc];
                    uint4 pw;
                    pw.x = h1u[a0];
                    pw.y = h1u[H1_P + a0];
                    pw.z = h1u[2 * H1_P + a0];
                    pw.w = h1u[3 * H1_P + a0];
                    af = __builtin_bit_cast(half8, pw);
                } else {
                    af = hz;
                }
                *accp = __builtin_amdgcn_mfma_f32_16x16x32_f16(af, bfr[kc], *accp, 0, 0, 0);
            }
        }
    }
    __syncthreads();                                   // xs dead -> h2p aliases it

    float* h2p = (float*)smem;                         // [144 pos][16 oc]
    if (wv_id < 3) {
        const int posb = (wv_id * 3) * 16 + quad * 4;
        #pragma unroll
        for (int r = 0; r < 4; ++r) h2p[(posb + r) * 16 + n]      = acc0[r];
        #pragma unroll
        for (int r = 0; r < 4; ++r) h2p[(posb + 16 + r) * 16 + n] = acc1[r];
        #pragma unroll
        for (int r = 0; r < 4; ++r) h2p[(posb + 32 + r) * 16 + n] = acc2[r];
    }
    __syncthreads();

    // ---- maxpool(2x2) + bias + relu + avg 6x6: 64 lanes --------------------
    if (t < 64) {
        const int oc = t >> 2, q = t & 3;
        const float bias = b2t[oc];
        float s = 0.f;
        #pragma unroll
        for (int r = 0; r < 9; ++r) {
            int idx = q * 9 + r;
            int pr = idx / 6, pc = idx % 6;
            int p00 = (2 * pr * 12 + 2 * pc) * 16 + oc;
            float m = fmaxf(fmaxf(h2p[p00], h2p[p00 + 16]),
                            fmaxf(h2p[p00 + 192], h2p[p00 + 208]));
            s += fmaxf(m + bias, 0.f);
        }
        s += __shfl_xor(s, 1);
        s += __shfl_xor(s, 2);
        if (q == 0) pool_s[oc] = s * (1.f / 36.f);
    }
    __syncthreads();

    // ---- fc1 (16->64) + relu + fc2 (64->4) in wave 0 -----------------------
    if (t < 64) {
        const float4* f4 = (const float4*)(fw1 + t * 16);
        float4 wa = f4[0], wb = f4[1], wc = f4[2], wd = f4[3];
        float a1 = fb1[t];
        a1 = fmaf(pool_s[0],  wa.x, a1); a1 = fmaf(pool_s[1],  wa.y, a1);
        a1 = fmaf(pool_s[2],  wa.z, a1); a1 = fmaf(pool_s[3],  wa.w, a1);
        a1 = fmaf(pool_s[4],  wb.x, a1); a1 = fmaf(pool_s[5],  wb.y, a1);
        a1 = fmaf(pool_s[6],  wb.z, a1); a1 = fmaf(pool_s[7],  wb.w, a1);
        a1 = fmaf(pool_s[8],  wc.x, a1); a1 = fmaf(pool_s[9],  wc.y, a1);
        a1 = fmaf(pool_s[10], wc.z, a1); a1 = fmaf(pool_s[11], wc.w, a1);
        a1 = fmaf(pool_s[12], wd.x, a1); a1 = fmaf(pool_s[13], wd.y, a1);
        a1 = fmaf(pool_s[14], wd.z, a1); a1 = fmaf(pool_s[15], wd.w, a1);
        float f = fmaxf(a1, 0.f);
        float p0 = f * fw2[t];
        float p1 = f * fw2[64 + t];
        float p2 = f * fw2[128 + t];
        float p3 = f * fw2[192 + t];
        #pragma unroll
        for (int off = 32; off > 0; off >>= 1) {
            p0 += __shfl_down(p0, off);
            p1 += __shfl_down(p1, off);
            p2 += __shfl_down(p2, off);
            p3 += __shfl_down(p3, off);
        }
        if (t == 0) {
            ((float4*)out_pre)[b] = make_float4(p0 + fb2[0], p1 + fb2[1],
                                                p2 + fb2[2], p3 + fb2[3]);
        }
    }
}

// ====== K2: BN1 (grid sync #1, M build overlapped) + quantum + BN2 =========
__global__ __launch_bounds__(256) void k_tail(
    float* __restrict__ out_pre,
    const float* __restrict__ ng, const float* __restrict__ nb,
    const float* __restrict__ theta,
    const float* __restrict__ u_re, const float* __restrict__ u_im,
    const float* __restrict__ qg, const float* __restrict__ qb,
    float* __restrict__ bins1, float* __restrict__ bins2,
    unsigned int* __restrict__ counters)
{
    __shared__ float red[256];
    __shared__ float ss1[8], ss2[8];
    __shared__ float2 A[256], B[256], Ms[256];
    const int t = threadIdx.x;
    const int sidx = blockIdx.x * 256 + t;

    float4 o4 = ((const float4*)out_pre)[sidx];
    A[t] = make_float2(u_re[t], u_im[t]);
    float th0 = theta[0], th1 = theta[1], th2 = theta[2], th3 = theta[3];

    float vals[8] = {o4.x, o4.y, o4.z, o4.w,
                     o4.x * o4.x, o4.y * o4.y, o4.z * o4.z, o4.w * o4.w};
    #pragma unroll
    for (int off = 32; off > 0; off >>= 1)
        #pragma unroll
        for (int k = 0; k < 8; ++k) vals[k] += __shfl_down(vals[k], off);
    if ((t & 63) == 0) {
        int wid = t >> 6;
        #pragma unroll
        for (int k = 0; k < 8; ++k) red[wid * 8 + k] = vals[k];
    }
    __syncthreads();
    if (t < 8) {
        float s = red[t] + red[8 + t] + red[16 + t] + red[24 + t];
        __hip_atomic_store(&bins1[blockIdx.x * 8 + t], s,
                           __ATOMIC_RELEASE, __HIP_MEMORY_SCOPE_AGENT);
    }
    __syncthreads();
    if (t == 0) { __threadfence(); atomicAdd(&counters[0], 1u); }

    __syncthreads();
    float c0 = cosf(0.5f * th0), s0 = sinf(0.5f * th0);
    apply_1q(A, B, t, make_float2(c0, 0), make_float2(0, -s0),
                      make_float2(0, -s0), make_float2(c0, 0), 3);   // RX wire0
    __syncthreads();
    float c1 = cosf(0.5f * th1), s1 = sinf(0.5f * th1);
    apply_1q(B, A, t, make_float2(c1, 0), make_float2(-s1, 0),
                      make_float2(s1, 0), make_float2(c1, 0), 2);    // RY wire1
    __syncthreads();
    float c2 = cosf(0.5f * th2), s2 = sinf(0.5f * th2);
    apply_1q(A, B, t, make_float2(c2, -s2), make_float2(0, 0),
                      make_float2(0, 0), make_float2(c2, s2), 1);    // RZ wire2
    __syncthreads();
    float c3 = cosf(0.5f * th3), s3 = sinf(0.5f * th3);
    apply_ctrl(B, A, t, make_float2(c3, 0), make_float2(0, -s3),
                        make_float2(0, -s3), make_float2(c3, 0), 3, 0); // CRX w0->w3
    __syncthreads();
    const float hh = 0.70710678118654752440f;
    apply_1q(A, B, t, make_float2(hh, 0), make_float2(hh, 0),
                      make_float2(hh, 0), make_float2(-hh, 0), 0);   // H wire3
    __syncthreads();
    apply_1q(B, A, t, make_float2(0.5f, 0.5f), make_float2(0.5f, -0.5f),
                      make_float2(0.5f, -0.5f), make_float2(0.5f, 0.5f), 1); // SX wire2
    __syncthreads();
    apply_ctrl(A, B, t, make_float2(0, 0), make_float2(1, 0),
                        make_float2(1, 0), make_float2(0, 0), 0, 3); // CX w3->w0
    __syncthreads();
    Ms[t] = B[t];

    if (t == 0) {
        while (__hip_atomic_load(&counters[0], __ATOMIC_ACQUIRE,
                                 __HIP_MEMORY_SCOPE_AGENT) < 32u)
            __builtin_amdgcn_s_sleep(4);
    }
    __syncthreads();
    red[t] = bins1[t];
    __syncthreads();
    if (t < 8) {
        float s = 0.f;
        for (int bb = 0; bb < 32; ++bb) s += red[bb * 8 + t];
        red[t] = s;
    }
    if (t < 4) {
        float mean = red[t] * (1.f / 8192.f);
        float var = red[4 + t] * (1.f / 8192.f) - mean * mean;
        float sc = ng[t] * rsqrtf(var + 1e-5f);
        ss1[t] = sc;
        ss1[4 + t] = nb[t] - mean * sc;
    }
    __syncthreads();

    float a[4];
    a[0] = fmaf(ss1[0], o4.x, ss1[4]);
    a[1] = fmaf(ss1[1], o4.y, ss1[5]);
    a[2] = fmaf(ss1[2], o4.z, ss1[6]);
    a[3] = fmaf(ss1[3], o4.w, ss1[7]);
    float2 v[4][2];
    #pragma unroll
    for (int w = 0; w < 4; ++w) {
        float s, c;
        __sincosf(0.5f * a[w], &s, &c);
        float2 v0 = make_float2(c * c, -c * s);
        float2 v1 = make_float2(s * c, s * s);
        float2 n0 = make_float2(c * v0.x + s * v1.y, c * v0.y - s * v1.x);
        float2 n1 = make_float2(s * v0.y + c * v1.x, -s * v0.x + c * v1.y);
        v[w][0] = make_float2(c * n0.x - s * n1.x, c * n0.y - s * n1.y);
        v[w][1] = make_float2(s * n0.x + c * n1.x, s * n0.y + c * n1.y);
    }
    float2 st[16];
    #pragma unroll
    for (int idx = 0; idx < 16; ++idx) {
        float2 p = cmul(v[0][(idx >> 3) & 1], v[1][(idx >> 2) & 1]);
        p = cmul(p, v[2][(idx >> 1) & 1]);
        st[idx] = cmul(p, v[3][idx & 1]);
    }
    float q[4] = {0.f, 0.f, 0.f, 0.f};
    #pragma unroll
    for (int j = 0; j < 16; ++j) {
        float2 acc = make_float2(0.f, 0.f);
        #pragma unroll
        for (int i = 0; i < 16; ++i) {
            float2 mm = Ms[j * 16 + i];
            acc.x = fmaf(mm.x, st[i].x, acc.x);
            acc.x = fmaf(-mm.y, st[i].y, acc.x);
            acc.y = fmaf(mm.x, st[i].y, acc.y);
            acc.y = fmaf(mm.y, st[i].x, acc.y);
        }
        float pr = acc.x * acc.x + acc.y * acc.y;
        q[0] += ((j >> 3) & 1) ? -pr : pr;
        q[1] += ((j >> 2) & 1) ? -pr : pr;
        q[2] += ((j >> 1) & 1) ? -pr : pr;
        q[3] += (j & 1) ? -pr : pr;
    }

    float vals2[8] = {q[0], q[1], q[2], q[3],
                      q[0] * q[0], q[1] * q[1], q[2] * q[2], q[3] * q[3]};
    #pragma unroll
    for (int off = 32; off > 0; off >>= 1)
        #pragma unroll
        for (int k = 0; k < 8; ++k) vals2[k] += __shfl_down(vals2[k], off);
    __syncthreads();
    if ((t & 63) == 0) {
        int wid = t >> 6;
        #pragma unroll
        for (int k = 0; k < 8; ++k) red[wid * 8 + k] = vals2[k];
    }
    __syncthreads();
    if (t < 8) {
        float s = red[t] + red[8 + t] + red[16 + t] + red[24 + t];
        __hip_atomic_store(&bins2[blockIdx.x * 8 + t], s,
                           __ATOMIC_RELEASE, __HIP_MEMORY_SCOPE_AGENT);
    }
    __syncthreads();
    if (t == 0) {
        __threadfence();
        atomicAdd(&counters[1], 1u);
        while (__hip_atomic_load(&counters[1], __ATOMIC_ACQUIRE,
                                 __HIP_MEMORY_SCOPE_AGENT) < 32u)
            __builtin_amdgcn_s_sleep(4);
    }
    __syncthreads();
    red[t] = bins2[t];
    __syncthreads();
    if (t < 8) {
        float s = 0.f;
        for (int bb = 0; bb < 32; ++bb) s += red[bb * 8 + t];
        red[t] = s;
    }
    if (t < 4) {
        float m2 = red[t] * (1.f / 8192.f);
        float v2 = red[4 + t] * (1.f / 8192.f) - m2 * m2;
        float sc = qg[t] * rsqrtf(v2 + 1e-5f);
        ss2[t] = sc;
        ss2[4 + t] = qb[t] - m2 * sc;
    }
    __syncthreads();

    float4 r;
    r.x = a[0] + fmaf(ss2[0], q[0], ss2[4]);
    r.y = a[1] + fmaf(ss2[1], q[1], ss2[5]);
    r.z = a[2] + fmaf(ss2[2], q[2], ss2[6]);
    r.w = a[3] + fmaf(ss2[3], q[3], ss2[7]);
    ((float4*)out_pre)[sidx] = r;
}

// ===========================================================================
extern "C" void kernel_launch(void* const* d_in, const int* in_sizes, int n_in,
                              void* d_out, int out_size, void* d_ws, size_t ws_size,
                              hipStream_t stream)
{
    const float* x     = (const float*)d_in[0];
    const float* w1    = (const float*)d_in[1];
    const float* b1    = (const float*)d_in[2];
    const float* w2    = (const float*)d_in[3];
    const float* b2    = (const float*)d_in[4];
    const float* fw1   = (const float*)d_in[5];
    const float* fb1   = (const float*)d_in[6];
    const float* fw2   = (const float*)d_in[7];
    const float* fb2   = (const float*)d_in[8];
    const float* ng    = (const float*)d_in[9];
    const float* nb    = (const float*)d_in[10];
    const float* theta = (const float*)d_in[11];
    const float* ure   = (const float*)d_in[12];
    const float* uim   = (const float*)d_in[13];
    const float* qg    = (const float*)d_in[14];
    const float* qb    = (const float*)d_in[15];

    float* ws = (float*)d_ws;
    unsigned int* counters = (unsigned int*)d_ws;   // [2]
    float* bins1 = ws + 16;                         // 256 floats
    float* bins2 = ws + 16 + 256;                   // 256 floats
    float* out_pre = (float*)d_out;

    k_cnn<<<8192, 256, 0, stream>>>(x, w1, b1, w2, b2, fw1, fb1, fw2, fb2,
                                    out_pre, counters);
    k_tail<<<32, 256, 0, stream>>>(out_pre, ng, nb, theta, ure, uim, qg, qb,
                                   bins1, bins2, counters);
}